// Round 7
// baseline (205.904 us; speedup 1.0000x reference)
//
#include <hip/hip_runtime.h>
#include <hip/hip_bf16.h>
#include <math.h>

// IDSCT2: out[b,u,v] = sum_{p,q} x[b,p,q] * S[u,p] * C[v,q]
// R12: parity fold kept (R8 math), but parities SPLIT ACROSS WAVES:
// waves 0-3 = E-GEMM, waves 4-7 = O-GEMM of the same 128x128 tile
// (wave w and w+4 own the same 64x64 sub-tile; 2x2 wave grid/parity).
// Why: R8-R11 counters show the dual-parity-per-wave design is LDS-pipe
// bound (128 KiB reads/tile/CU vs 1024 cy MFMA) at 2 waves/SIMD (acc=128
// VGPR) with 1 block/CU (144 KiB LDS) -- no TLP to fill either pipe;
// 3 schedule fixes were all neutral. Splitting halves acc (64 VGPR) and
// LDS (64 KiB double-buffered) -> __launch_bounds__(512,4) caps VGPR at
// 128 -> 4 waves/SIMD AND 2 blocks/CU (grid 512 = exactly 2/CU).
// E/O combine: one-time LDS exchange after the K-loop (O-waves write acc
// col-major b128 + XOR swizzle; E-waves read, fold e+o / e-o, store both
// output rows).
// K-loop (double buffer, counted vmcnt): per tile
//   {8 ds_read_b128; 16 MFMA; barrier (all reads of buf c retired);
//    4 glds stage tile t+2 into buf c; vmcnt(4) (retires t+1's 4, never
//    drains); barrier (publish t+1)}.
//   C[2047-v,q] = (-1)^q C[v,q];  S[2047-u,p] = -(-1)^p S[u,p]
// pass1: Et/Ot (even/odd q), tT[v']=Et+Ot, tT[2047-v']=Et-Ot, output
// p-parity-split (tTe/tTo) to feed pass2 directly.
// pass2: E2/O2 (even/odd p), out[u']=E2+O2, out[2047-u']=O2-E2 (fp32).
// Swizzle (both-sides, rule #21): 64B rows = 4 chunks; slot =
// chunk ^ ((row>>1)&3) via pre-swizzled global src (linear glds dest);
// ds_read applies the same XOR -> conflict-free b128 (R8-R11 measured 0).

#define BM 128   // output rows per block (v' / u')
#define BN 128   // output cols per block (p / v)
#define BK 32
#define KDIM 1024

typedef __bf16 bf16x8 __attribute__((ext_vector_type(8)));
typedef __bf16 bf16x4 __attribute__((ext_vector_type(4)));
typedef float floatx4 __attribute__((ext_vector_type(4)));

__device__ __forceinline__ void async_ld16(const void* g, void* l) {
    __builtin_amdgcn_global_load_lds(
        (__attribute__((address_space(1))) void*)(g),
        (__attribute__((address_space(3))) void*)(l), 16, 0, 0);
}

#define BARX() __builtin_amdgcn_s_barrier()
#define VM4() asm volatile("s_waitcnt vmcnt(4)" ::: "memory")
#define VM0() asm volatile("s_waitcnt vmcnt(0)" ::: "memory")
#define NOPSTMT ((void)0)

// Basis + deinterleave-convert x. Integer phase mod 8192 keeps trig arg
// exact: arg = pi/4096 * phase.
//   Ce[v',j]=cos(pi(2v'+1)(2j)/4096)   Co: (2j+1)
//   Se[u',m]=sin(pi(2u'+1)(2m)/4096)   So: (2m+1)
//   xe[b,p,m]=x[b,p,2m]  xo: 2m+1
__global__ void prep_kernel(const float4* __restrict__ x,
                            bf16x4* __restrict__ xe, bf16x4* __restrict__ xo,
                            __bf16* __restrict__ Ce, __bf16* __restrict__ Co,
                            __bf16* __restrict__ Se, __bf16* __restrict__ So) {
    int b = blockIdx.x;
    if (b < 4096) {  // 1M basis entries
        int idx = b * 256 + threadIdx.x;
        int vp = idx >> 10;
        int j = idx & 1023;
        int pe = ((2 * vp + 1) * (2 * j)) & 8191;
        int po = ((2 * vp + 1) * (2 * j + 1)) & 8191;
        float ae = (float)pe * 7.669903939428206e-04f;  // pi/4096
        float ao = (float)po * 7.669903939428206e-04f;
        float se, ce, so, co;
        __sincosf(ae, &se, &ce);
        __sincosf(ao, &so, &co);
        Ce[idx] = (__bf16)ce;
        Co[idx] = (__bf16)co;
        Se[idx] = (__bf16)se;
        So[idx] = (__bf16)so;
    } else {  // 2M threads, 8 floats each
        int g = (b - 4096) * 256 + threadIdx.x;
        float4 v0 = x[2 * g];
        float4 v1 = x[2 * g + 1];
        bf16x4 e, o;
        e[0] = (__bf16)v0.x; e[1] = (__bf16)v0.z;
        e[2] = (__bf16)v1.x; e[3] = (__bf16)v1.z;
        o[0] = (__bf16)v0.y; o[1] = (__bf16)v0.w;
        o[2] = (__bf16)v1.y; o[3] = (__bf16)v1.w;
        xe[g] = e;
        xo[g] = o;
    }
}

// Parity-folded NT GEMM, parity-split waves. A{e,o}: [1024][1024].
// B{e,o}: [z][2048][1024]. PASS=1: D0/D1 = tTe/tTo [z][2048][1024] bf16.
// PASS=2: Df = out [z][2048][2048] fp32.
template <int PASS>
__global__ void __launch_bounds__(512, 4) gemm_eo(
    const __bf16* __restrict__ Ae, const __bf16* __restrict__ Ao,
    const __bf16* __restrict__ Be, const __bf16* __restrict__ Bo,
    __bf16* __restrict__ D0, __bf16* __restrict__ D1,
    float* __restrict__ Df) {
    // per buffer: Ae[128*32] Ao[128*32] Be[128*32] Bo[128*32] = 16384 elems
    __shared__ __bf16 lds[2][16384];  // 64 KiB -> 2 blocks/CU
    constexpr int OFF_AE = 0, OFF_AO = 4096, OFF_BE = 8192, OFF_BO = 12288;

    const int tid = threadIdx.x;
    const int lane = tid & 63;
    const int wave = tid >> 6;   // 0..7
    const int par = wave >> 2;   // 0 = E-waves, 1 = O-waves
    const int wr = (wave >> 1) & 1;  // 2x2 grid per parity, 64x64 tiles
    const int wc = wave & 1;

    const size_t zB = (size_t)blockIdx.z * 2048 * 1024;
    Be += zB; Bo += zB;

    const int row0 = blockIdx.y * BM;   // v'/u' in [0,1024)
    const int col0 = blockIdx.x * BN;   // p/v  in [0,2048)

    // ---- staging: each wave stages chunk `wave` (16 rows) of all four
    // operand regions = 4 glds/tile. Lane l -> row wave*16 + (l>>2),
    // slot l&3; global chunk = slot ^ ((row>>1)&3) = slot ^ ((l>>3)&3).
    const int srow = wave * 16 + (lane >> 2);  // 0..127
    const int sgc = ((lane & 3) ^ ((lane >> 3) & 3)) * 8;
    const __bf16* aeS = Ae + (size_t)(row0 + srow) * KDIM + sgc;
    const __bf16* aoS = Ao + (size_t)(row0 + srow) * KDIM + sgc;
    const __bf16* beS = Be + (size_t)(col0 + srow) * KDIM + sgc;
    const __bf16* boS = Bo + (size_t)(col0 + srow) * KDIM + sgc;
    const int ldsW = wave << 9;  // wave-uniform dest base (elems)

    auto STG = [&](int s, int kt) {
        const size_t ko = (size_t)kt * BK;
        async_ld16(aeS + ko, &lds[s][OFF_AE + ldsW]);
        async_ld16(aoS + ko, &lds[s][OFF_AO + ldsW]);
        async_ld16(beS + ko, &lds[s][OFF_BE + ldsW]);
        async_ld16(boS + ko, &lds[s][OFF_BO + ldsW]);
    };

    // ---- fragment reads: m/n = lane&15 (+16*frag), k-chunk = lane>>4;
    // stored slot = chunk ^ ((fr>>1)&3) -> conflict-free b128.
    const int fr = lane & 15;
    const int fc = lane >> 4;
    const int slotOff = (fc ^ ((fr >> 1) & 3)) * 8;
    const int aBase = (par ? OFF_AO : OFF_AE) + (wr * 64 + fr) * BK + slotOff;
    const int bBase = (par ? OFF_BO : OFF_BE) + (wc * 64 + fr) * BK + slotOff;

    bf16x8 af[4], bf[4];
    floatx4 acc[4][4] = {};

    auto LDF = [&](int buf) {
#pragma unroll
        for (int i = 0; i < 4; ++i)
            af[i] = *(const bf16x8*)&lds[buf][aBase + i * 16 * BK];
#pragma unroll
        for (int j = 0; j < 4; ++j)
            bf[j] = *(const bf16x8*)&lds[buf][bBase + j * 16 * BK];
    };
    auto MMA16 = [&]() {
        __builtin_amdgcn_s_setprio(1);
#pragma unroll
        for (int i = 0; i < 4; ++i)
#pragma unroll
            for (int j = 0; j < 4; ++j)
                acc[i][j] = __builtin_amdgcn_mfma_f32_16x16x32_bf16(
                    af[i], bf[j], acc[i][j], 0, 0, 0);
        __builtin_amdgcn_s_setprio(0);
    };

    // Double-buffer tile: reads of buf c retire before MMA issues
    // (operand dep), barrier -> safe to stage t+2 into buf c; vmcnt(4)
    // retires t+1's 4 glds (counted, never drains); barrier publishes.
#define TILE(bc, SG, VMW) do {          \
        LDF(bc); MMA16(); BARX();       \
        SG; VMW; BARX();                \
    } while (0)

    // Prologue: stage tiles 0,1 (8 glds); vmcnt(4) retires tile 0.
    STG(0, 0); STG(1, 1);
    VM4();
    BARX();

    // 32 K-tiles; unroll by 2 for static buffer indices.
    for (int i = 0; i < 15; ++i) {
        const int t = 2 * i;
        TILE(0, STG(0, t + 2), VM4());
        TILE(1, STG(1, t + 3), VM4());
    }
    TILE(0, NOPSTMT, VM0());   // tile 30: drain tile 31's glds
    TILE(1, NOPSTMT, NOPSTMT); // tile 31 (trailing barrier guards LDS reuse)
#undef TILE

    // ---- E/O combine via LDS (one-time). O-waves write acc col-major
    // (r-contiguous -> b128) at float offset lj*128 + (li0 ^ ((lj&7)<<3))
    // (XOR spreads the stride-128 columns over banks); E-waves read the
    // same addresses, fold, and store both output rows.
    float* ldsF = (float*)&lds[0][0];  // 16384 floats = 64 KiB
    const int ecol = lane & 15;        // C/D layout (verified R1)
    const int erow = (lane >> 4) * 4;
    if (par == 1) {
#pragma unroll
        for (int i = 0; i < 4; ++i)
#pragma unroll
            for (int j = 0; j < 4; ++j) {
                const int li0 = wr * 64 + i * 16 + erow;
                const int lj = wc * 64 + j * 16 + ecol;
                *(floatx4*)&ldsF[lj * 128 + (li0 ^ ((lj & 7) << 3))] = acc[i][j];
            }
    }
    __syncthreads();
    if (par == 0) {
#pragma unroll
        for (int i = 0; i < 4; ++i)
#pragma unroll
            for (int j = 0; j < 4; ++j) {
                const int li0 = wr * 64 + i * 16 + erow;
                const int lj = wc * 64 + j * 16 + ecol;
                const floatx4 o4 =
                    *(const floatx4*)&ldsF[lj * 128 + (li0 ^ ((lj & 7) << 3))];
#pragma unroll
                for (int r = 0; r < 4; ++r) {
                    const int gi = row0 + li0 + r;
                    const int gj = col0 + lj;
                    const float e = acc[i][j][r];
                    const float o = o4[r];
                    if (PASS == 1) {
                        // tT[gi] = e+o ; tT[2047-gi] = e-o ; col-parity split
                        __bf16* base = (gj & 1) ? D1 : D0;
                        base += zB;
                        const size_t m = (size_t)(gj >> 1);
                        base[(size_t)gi * 1024 + m] = (__bf16)(e + o);
                        base[(size_t)(2047 - gi) * 1024 + m] = (__bf16)(e - o);
                    } else {
                        // out[gi] = e+o ; out[2047-gi] = o-e
                        float* ob = Df + (size_t)blockIdx.z * 2048 * 2048;
                        ob[(size_t)gi * 2048 + gj] = e + o;
                        ob[(size_t)(2047 - gi) * 2048 + gj] = o - e;
                    }
                }
            }
    }
}

extern "C" void kernel_launch(void* const* d_in, const int* in_sizes, int n_in,
                              void* d_out, int out_size, void* d_ws, size_t ws_size,
                              hipStream_t stream) {
    const float* x = (const float*)d_in[0];
    float* out = (float*)d_out;

    const size_t m1 = (size_t)1024 * 1024;  // basis elems (2 MiB each)
    const size_t hm = (size_t)4 * 2048 * 1024;  // half-matrix batch: 8M elems

    // Workspace (72 MiB): Ce,Co,Se,So (8 MiB) | xe,xo (32) | tTe,tTo (32)
    __bf16* Ce = (__bf16*)d_ws;
    __bf16* Co = Ce + m1;
    __bf16* Se = Co + m1;
    __bf16* So = Se + m1;
    __bf16* xe = So + m1;
    __bf16* xo = xe + hm;
    __bf16* tTe = xo + hm;
    __bf16* tTo = tTe + hm;

    // 4096 basis blocks + 8192 deinterleave blocks
    prep_kernel<<<12288, 256, 0, stream>>>((const float4*)x, (bf16x4*)xe,
                                           (bf16x4*)xo, Ce, Co, Se, So);

    dim3 grid(2048 / BN, 1024 / BM, 4);  // (16, 8, 4) = 512 blocks = 2/CU
    // pass1: Et/Ot over q-parity; epilogue folds v' and splits p-parity
    gemm_eo<1><<<grid, 512, 0, stream>>>(Ce, Co, xe, xo, tTe, tTo, nullptr);
    // pass2: E2/O2 over p-parity; epilogue folds u', writes fp32 out
    gemm_eo<2><<<grid, 512, 0, stream>>>(Se, So, tTe, tTo, nullptr, nullptr, out);
}